// Round 6
// baseline (462.210 us; speedup 1.0000x reference)
//
#include <hip/hip_runtime.h>
#include <hip/hip_bf16.h>

#define B_ 2
#define T_ 1024
#define C_ 1024
#define H_ 16

typedef short bf16x8 __attribute__((ext_vector_type(8)));
typedef float f32x4 __attribute__((ext_vector_type(4)));

#define MFMA16(a, b, c) __builtin_amdgcn_mfma_f32_16x16x32_bf16(a, b, c, 0, 0, 0)
#define EXP2F(x) __builtin_amdgcn_exp2f(x)
#define SCL 0.36067376f   // 0.25 * log2(e): exp(s/4) = 2^(s*SCL)

__device__ inline short f2bf(float x) {
    union { __hip_bfloat16 h; short s; } u;
    u.h = __float2bfloat16(x);
    return u.s;
}

__device__ inline void gl_lds16(const void* g, void* l) {
    __builtin_amdgcn_global_load_lds(
        (const __attribute__((address_space(1))) unsigned int*)g,
        (__attribute__((address_space(3))) unsigned int*)l, 16, 0, 0);
}

// ---------------------------------------------------------------------------
// x (fp32) -> xb (bf16), flat. 2M elems, 8/thread.
// ---------------------------------------------------------------------------
__global__ __launch_bounds__(256) void cvt_x(const float* __restrict__ x,
                                             short* __restrict__ xb) {
    int idx = (blockIdx.x * 256 + threadIdx.x) * 8;
    float4 a = *(const float4*)(x + idx);
    float4 b = *(const float4*)(x + idx + 4);
    bf16x8 v;
    v[0] = f2bf(a.x); v[1] = f2bf(a.y); v[2] = f2bf(a.z); v[3] = f2bf(a.w);
    v[4] = f2bf(b.x); v[5] = f2bf(b.y); v[6] = f2bf(b.z); v[7] = f2bf(b.w);
    *(bf16x8*)(xb + idx) = v;
}

// ---------------------------------------------------------------------------
// Wt[(h*1024+n)][c] = bf16(W[h*1024+c][n]) — one-time transpose+convert.
// ---------------------------------------------------------------------------
__global__ __launch_bounds__(256) void cvt_w(const float* __restrict__ W,
                                             short* __restrict__ Wt) {
    __shared__ float T[64][65];
    const int bid = blockIdx.x;
    const int nb = bid & 15, cb = (bid >> 4) & 15, h = bid >> 8;
    const int t = threadIdx.x;
    const int c0 = cb * 64, n0 = nb * 64;
    const float* src = W + (size_t)(h * 1024 + c0) * 1024 + n0;
    {
        const int cl = t >> 4, nl = (t & 15) * 4;
#pragma unroll
        for (int r = 0; r < 4; ++r) {
            float4 v = *(const float4*)(src + (size_t)(cl + r * 16) * 1024 + nl);
            T[cl + r * 16][nl + 0] = v.x;
            T[cl + r * 16][nl + 1] = v.y;
            T[cl + r * 16][nl + 2] = v.z;
            T[cl + r * 16][nl + 3] = v.w;
        }
    }
    __syncthreads();
    {
        short* dst = Wt + (size_t)(h * 1024 + n0) * 1024 + c0;
        const int nl = t >> 3, cl8 = (t & 7) * 8;
#pragma unroll
        for (int r = 0; r < 2; ++r) {
            const int n = nl + r * 32;
            bf16x8 o;
#pragma unroll
            for (int j = 0; j < 8; ++j) o[j] = f2bf(T[cl8 + j][n]);
            *(bf16x8*)(dst + (size_t)n * 1024 + cl8) = o;
        }
    }
}

// ---------------------------------------------------------------------------
// zgemm4 (m97 replica): ZT2[m][sg] = sum_c Wt[m][c] * xb[sg][c],
// m over 16384 (h,n), sg over 2048 (b,s). 128x128 tile, BK=32, 256 thr,
// 4 waves in 2x2 quadrants, global_load_lds staging, LDS-transpose epilogue.
// ---------------------------------------------------------------------------
__global__ __launch_bounds__(256) void zgemm4(const short* __restrict__ xb,
                                              const short* __restrict__ Wt,
                                              short* __restrict__ ZT2) {
    __shared__ short SMEM[9216];      // staging 8192 shorts; epilogue 9216
    short* Al = SMEM;                 // [4 kg][128 m][8]
    short* Bl = SMEM + 4096;          // [4 kg][128 s][8]

    const int bid = blockIdx.x;
    const int nt = bid & 15, mt = bid >> 4;
    const int m0 = mt * 128, n0 = nt * 128;
    const int t = threadIdx.x;
    const int lane = t & 63, q = lane >> 4, l16 = lane & 15;
    const int w = t >> 6, wm = (w & 1) * 64, wn = (w >> 1) * 64;

    const short* Ab = Wt + (size_t)m0 * 1024;
    const short* Bb = xb + (size_t)n0 * 1024;
    const int srow = t & 127, skg = t >> 7;     // 0..127, 0..1
    char* al0 = (char*)Al + (size_t)t * 16;
    char* bl0 = (char*)Bl + (size_t)t * 16;

    f32x4 acc[4][4];
#pragma unroll
    for (int i = 0; i < 4; ++i)
#pragma unroll
        for (int j = 0; j < 4; ++j) acc[i][j] = (f32x4){0.f, 0.f, 0.f, 0.f};

    for (int k0 = 0; k0 < 1024; k0 += 32) {
        __syncthreads();
        gl_lds16(Ab + (size_t)srow * 1024 + k0 + skg * 8, al0);
        gl_lds16(Ab + (size_t)srow * 1024 + k0 + (skg + 2) * 8, al0 + 4096);
        gl_lds16(Bb + (size_t)srow * 1024 + k0 + skg * 8, bl0);
        gl_lds16(Bb + (size_t)srow * 1024 + k0 + (skg + 2) * 8, bl0 + 4096);
        __syncthreads();
        bf16x8 af[4], bfr[4];
#pragma unroll
        for (int i = 0; i < 4; ++i)
            af[i] = *(bf16x8*)&Al[(q * 128 + wm + i * 16 + l16) * 8];
#pragma unroll
        for (int j = 0; j < 4; ++j)
            bfr[j] = *(bf16x8*)&Bl[(q * 128 + wn + j * 16 + l16) * 8];
#pragma unroll
        for (int i = 0; i < 4; ++i)
#pragma unroll
            for (int j = 0; j < 4; ++j)
                acc[i][j] = MFMA16(af[i], bfr[j], acc[i][j]);
    }

    // Epilogue: per-wave LDS transpose -> 16B coalesced stores into ZT2.
    __syncthreads();
    short* Cw = SMEM + w * 2304;      // [32][72] per wave
    const int lr2 = lane >> 1, ch = lane & 1;
#pragma unroll
    for (int p2 = 0; p2 < 2; ++p2) {
#pragma unroll
        for (int i2 = 0; i2 < 2; ++i2) {
            const int i = p2 * 2 + i2, row = i2 * 16 + q * 4;
#pragma unroll
            for (int j = 0; j < 4; ++j)
#pragma unroll
                for (int r = 0; r < 4; ++r)
                    Cw[(row + r) * 72 + j * 16 + l16] = f2bf(acc[i][j][r]);
        }
        const size_t m_abs = m0 + wm + p2 * 32 + lr2;
#pragma unroll
        for (int u = 0; u < 4; ++u) {
            bf16x8 v = *(bf16x8*)&Cw[lr2 * 72 + ch * 32 + u * 8];
            *(bf16x8*)(ZT2 + m_abs * 2048 + n0 + wn + ch * 32 + u * 8) = v;
        }
    }
}

// ---------------------------------------------------------------------------
// pgen: P[b][h][t][s] = exp(score/4)/l_row, causal (static-max softmax:
// logits bounded, fp32 exp can't overflow; common factor divides out).
// Two-pass recompute (QK is cheap). Grid (b,h,64-row tile) = 512 blocks,
// 4 waves of 16 rows. Even tiles zero-fill one extra 64-chunk so pzgemm's
// 128-row tiles never read uninitialized P.
// ---------------------------------------------------------------------------
__global__ __launch_bounds__(256) void pgen(const short* __restrict__ xb,
                                            short* __restrict__ P) {
    __shared__ short Pw[4][16][72];

    const int bid = blockIdx.x;
    const int tb = bid & 15, h = (bid >> 4) & 15, b = bid >> 8;
    const int t0 = tb * 64;
    const int t = threadIdx.x;
    const int lane = t & 63, q = lane >> 4, l16 = lane & 15;
    const int w = t >> 6;                       // wave = 16-row group
    const short* xbb = xb + ((size_t)b << 20);
    short* Pb = P + (((size_t)(b * 16 + h)) << 20);

    bf16x8 qf[2];
#pragma unroll
    for (int ks = 0; ks < 2; ++ks)
        qf[ks] = *(const bf16x8*)(xbb + (size_t)(t0 + w * 16 + l16) * 1024 +
                                  h * 64 + ks * 32 + q * 8);

    // Pass 1: row sums.
    float l_r[4] = {0.f, 0.f, 0.f, 0.f};
    for (int ci = 0; ci <= tb; ++ci) {
        const int s0 = ci * 64;
        f32x4 sf[4];
#pragma unroll
        for (int st = 0; st < 4; ++st) sf[st] = (f32x4){0.f, 0.f, 0.f, 0.f};
#pragma unroll
        for (int st = 0; st < 4; ++st)
#pragma unroll
            for (int ks = 0; ks < 2; ++ks) {
                bf16x8 kf = *(const bf16x8*)(xbb +
                    (size_t)(s0 + st * 16 + l16) * 1024 + h * 64 + ks * 32 + q * 8);
                sf[st] = MFMA16(qf[ks], kf, sf[st]);
            }
#pragma unroll
        for (int st = 0; st < 4; ++st)
#pragma unroll
            for (int r = 0; r < 4; ++r) {
                float pv = EXP2F(sf[st][r] * SCL);
                if (s0 + st * 16 + l16 > t0 + w * 16 + q * 4 + r) pv = 0.f;
                l_r[r] += pv;
            }
    }
    float inv[4];
#pragma unroll
    for (int r = 0; r < 4; ++r) {
        l_r[r] += __shfl_xor(l_r[r], 1);
        l_r[r] += __shfl_xor(l_r[r], 2);
        l_r[r] += __shfl_xor(l_r[r], 4);
        l_r[r] += __shfl_xor(l_r[r], 8);
        inv[r] = 1.f / l_r[r];
    }

    // Pass 2: recompute, scale, store via per-wave LDS transpose.
    for (int ci = 0; ci <= tb; ++ci) {
        const int s0 = ci * 64;
        f32x4 sf[4];
#pragma unroll
        for (int st = 0; st < 4; ++st) sf[st] = (f32x4){0.f, 0.f, 0.f, 0.f};
#pragma unroll
        for (int st = 0; st < 4; ++st)
#pragma unroll
            for (int ks = 0; ks < 2; ++ks) {
                bf16x8 kf = *(const bf16x8*)(xbb +
                    (size_t)(s0 + st * 16 + l16) * 1024 + h * 64 + ks * 32 + q * 8);
                sf[st] = MFMA16(qf[ks], kf, sf[st]);
            }
#pragma unroll
        for (int st = 0; st < 4; ++st)
#pragma unroll
            for (int r = 0; r < 4; ++r) {
                float pv = EXP2F(sf[st][r] * SCL) * inv[r];
                if (s0 + st * 16 + l16 > t0 + w * 16 + q * 4 + r) pv = 0.f;
                Pw[w][q * 4 + r][st * 16 + l16] = f2bf(pv);
            }
        // wave-local LDS write->read; DS pipe is in-order within the wave
        short* prow = Pb + (size_t)(t0 + w * 16 + l16) * 1024 + s0;
        *(bf16x8*)(prow + q * 8)      = *(bf16x8*)&Pw[w][l16][q * 8];
        *(bf16x8*)(prow + 32 + q * 8) = *(bf16x8*)&Pw[w][l16][32 + q * 8];
    }
    // Even tile: zero chunk tb+1 (read by pzgemm's 128-row tiles).
    if (!(tb & 1)) {
        bf16x8 z = {0, 0, 0, 0, 0, 0, 0, 0};
        short* prow = Pb + (size_t)(t0 + w * 16 + l16) * 1024 + (tb + 1) * 64;
        *(bf16x8*)(prow + q * 8)      = z;
        *(bf16x8*)(prow + 32 + q * 8) = z;
    }
}

// ---------------------------------------------------------------------------
// pzgemm (m97 replica + causal cutoff + 4-way head split-K):
// out[b*1024+t][n] += sum_{h in grp} sum_{s<t0+128} P[b][h][t][s]*ZT2[(h,n)][(b,s)]
// 128x128 tile, BK=32; heavy t-tiles dispatched first; fp32 atomic epilogue.
// ---------------------------------------------------------------------------
__global__ __launch_bounds__(256) void pzgemm(const short* __restrict__ P,
                                              const short* __restrict__ ZT2,
                                              float* __restrict__ out) {
    __shared__ short SMEM[8192];
    short* Al = SMEM;                 // [4 kg][128 t][8]
    short* Bl = SMEM + 4096;          // [4 kg][128 n][8]

    const int bid = blockIdx.x;
    const int nt = bid & 7;                       // n-tile (XCD spread)
    const int tt = 7 - ((bid >> 3) & 7);          // heavy (large t0) first
    const int b = (bid >> 6) & 1, grp = bid >> 7; // 4 head-groups
    const int t0 = tt * 128, n0 = nt * 128;
    const int t = threadIdx.x;
    const int lane = t & 63, q = lane >> 4, l16 = lane & 15;
    const int w = t >> 6, wm = (w & 1) * 64, wn = (w >> 1) * 64;
    const int srow = t & 127, skg = t >> 7;
    char* al0 = (char*)Al + (size_t)t * 16;
    char* bl0 = (char*)Bl + (size_t)t * 16;
    const int send = t0 + 128;                    // causal K bound (<=1024)

    f32x4 acc[4][4];
#pragma unroll
    for (int i = 0; i < 4; ++i)
#pragma unroll
        for (int j = 0; j < 4; ++j) acc[i][j] = (f32x4){0.f, 0.f, 0.f, 0.f};

    for (int hh = 0; hh < 4; ++hh) {
        const int h = grp * 4 + hh;
        const short* Ab = P + (((size_t)(b * 16 + h)) << 20) + (size_t)t0 * 1024;
        const short* Bb = ZT2 + (size_t)(h * 1024 + n0) * 2048 + b * 1024;
        for (int s0 = 0; s0 < send; s0 += 32) {
            __syncthreads();
            gl_lds16(Ab + (size_t)srow * 1024 + s0 + skg * 8, al0);
            gl_lds16(Ab + (size_t)srow * 1024 + s0 + (skg + 2) * 8, al0 + 4096);
            gl_lds16(Bb + (size_t)srow * 2048 + s0 + skg * 8, bl0);
            gl_lds16(Bb + (size_t)srow * 2048 + s0 + (skg + 2) * 8, bl0 + 4096);
            __syncthreads();
            bf16x8 af[4], bfr[4];
#pragma unroll
            for (int i = 0; i < 4; ++i)
                af[i] = *(bf16x8*)&Al[(q * 128 + wm + i * 16 + l16) * 8];
#pragma unroll
            for (int j = 0; j < 4; ++j)
                bfr[j] = *(bf16x8*)&Bl[(q * 128 + wn + j * 16 + l16) * 8];
#pragma unroll
            for (int i = 0; i < 4; ++i)
#pragma unroll
                for (int j = 0; j < 4; ++j)
                    acc[i][j] = MFMA16(af[i], bfr[j], acc[i][j]);
        }
    }

    // Epilogue: head-group partial sums -> fp32 atomics (out pre-zeroed).
#pragma unroll
    for (int i = 0; i < 4; ++i)
#pragma unroll
        for (int j = 0; j < 4; ++j) {
            size_t base = (size_t)(b * 1024 + t0 + wm + i * 16 + q * 4) * 1024 +
                          n0 + wn + j * 16 + l16;
            atomicAdd(out + base,        acc[i][j][0]);
            atomicAdd(out + base + 1024, acc[i][j][1]);
            atomicAdd(out + base + 2048, acc[i][j][2]);
            atomicAdd(out + base + 3072, acc[i][j][3]);
        }
}

// ===========================================================================
// Fallback path (ws < 132 MiB): round-5 proven kernels.
// ===========================================================================
#define ZPAD 40

__global__ __launch_bounds__(256, 2) void zgemm_sm(const short* __restrict__ xb,
                                                   const float* __restrict__ W,
                                                   short* __restrict__ ZT) {
    __shared__ short Wts[128 * ZPAD];
    __shared__ short Xs[2][128 * ZPAD];

    const int tid = threadIdx.x;
    const int bs = blockIdx.x & 7;
    const int bn = (blockIdx.x >> 3) & 7;
    const int h  = blockIdx.x >> 6;
    const int s0 = bs * 128, n0 = bn * 128;
    const int lane = tid & 63, q = lane >> 4, l16 = lane & 15;
    const int w = tid >> 6, bw = w >> 1, sh = w & 1;

    f32x4 acc[8][4];
#pragma unroll
    for (int i = 0; i < 8; ++i)
#pragma unroll
        for (int j = 0; j < 4; ++j) acc[i][j] = (f32x4){0.f, 0.f, 0.f, 0.f};

    for (int k0 = 0; k0 < 1024; k0 += 32) {
        __syncthreads();
#pragma unroll
        for (int r = 0; r < 2; ++r) {
            const int c2 = ((tid >> 5) << 1) + (r << 4);
            const float* w0p = W + (size_t)(h * 1024 + k0 + c2) * 1024 + n0;
            const float* w1p = w0p + 1024;
#pragma unroll
            for (int i = 0; i < 4; ++i) {
                const int n = (tid & 31) + (i << 5);
                float wa = w0p[n], wb = w1p[n];
                unsigned u = (unsigned)(unsigned short)f2bf(wa) |
                             ((unsigned)(unsigned short)f2bf(wb) << 16);
                *(unsigned*)&Wts[n * ZPAD + c2] = u;
            }
        }
#pragma unroll
        for (int i = 0; i < 4; ++i) {
            const int id = tid + (i << 8);
            const int b2 = id >> 9, s = (id >> 2) & 127, cg = id & 3;
            bf16x8 v = *(const bf16x8*)(xb + (size_t)b2 * (T_ * C_) +
                                        (size_t)(s0 + s) * 1024 + k0 + cg * 8);
            *(bf16x8*)&Xs[b2][s * ZPAD + cg * 8] = v;
        }
        __syncthreads();

        bf16x8 af[8], bfr[4];
#pragma unroll
        for (int ntv = 0; ntv < 8; ++ntv)
            af[ntv] = *(bf16x8*)&Wts[(ntv * 16 + l16) * ZPAD + q * 8];
#pragma unroll
        for (int st = 0; st < 4; ++st)
            bfr[st] = *(bf16x8*)&Xs[bw][(sh * 64 + st * 16 + l16) * ZPAD + q * 8];
#pragma unroll
        for (int ntv = 0; ntv < 8; ++ntv)
#pragma unroll
            for (int st = 0; st < 4; ++st)
                acc[ntv][st] = MFMA16(af[ntv], bfr[st], acc[ntv][st]);
    }

    short* zb = ZT + (size_t)(bw * 16 + h) * (1024 * 1024);
#pragma unroll
    for (int ntv = 0; ntv < 8; ++ntv)
#pragma unroll
        for (int st = 0; st < 4; ++st)
#pragma unroll
            for (int r = 0; r < 4; ++r) {
                int n_abs = n0 + ntv * 16 + q * 4 + r;
                int s_abs = s0 + sh * 64 + st * 16 + l16;
                zb[(size_t)n_abs * 1024 + s_abs] = f2bf(acc[ntv][st][r]);
            }
}

__global__ __launch_bounds__(512, 4) void attn_fb(const short* __restrict__ xb,
                                                  const short* __restrict__ ZT,
                                                  float* __restrict__ out) {
    __shared__ short Pb[2][64][72];
    __shared__ float row_l[64];

    const int tid = threadIdx.x;
    const int bh = blockIdx.x & 31;
    const int chhalf = (blockIdx.x >> 5) & 1;
    const int p = blockIdx.x >> 6;
    const int b = bh >> 4, h = bh & 15;
    const int lane = tid & 63, q = lane >> 4, l16 = lane & 15;
    const int w = tid >> 6;
    const int chb = chhalf * 512 + w * 64;
    const short* xbb = xb + ((size_t)b << 20);
    const short* ztb = ZT + ((size_t)(b * 16 + h) << 20);

    const int tiles[2] = { p, 15 - p };
    for (int ti = 0; ti < 2; ++ti) {
        const int tb = tiles[ti], t0 = tb * 64, nch = tb + 1;

        f32x4 acc[4][4];
#pragma unroll
        for (int mt = 0; mt < 4; ++mt)
#pragma unroll
            for (int nt = 0; nt < 4; ++nt) acc[mt][nt] = (f32x4){0.f, 0.f, 0.f, 0.f};
        float l_r[4] = {0.f, 0.f, 0.f, 0.f};

        __syncthreads();

        bf16x8 qf[2];
        if (w < 4) {
#pragma unroll
            for (int ks = 0; ks < 2; ++ks)
                qf[ks] = *(const bf16x8*)(xbb + (size_t)(t0 + w * 16 + l16) * 1024 +
                                          h * 64 + ks * 32 + q * 8);
            {
                f32x4 sf[4];
#pragma unroll
                for (int st = 0; st < 4; ++st) sf[st] = (f32x4){0.f, 0.f, 0.f, 0.f};
#pragma unroll
                for (int st = 0; st < 4; ++st)
#pragma unroll
                    for (int ks = 0; ks < 2; ++ks) {
                        bf16x8 kf = *(const bf16x8*)(xbb +
                            (size_t)(st * 16 + l16) * 1024 + h * 64 + ks * 32 + q * 8);
                        sf[st] = MFMA16(qf[ks], kf, sf[st]);
                    }
#pragma unroll
                for (int st = 0; st < 4; ++st)
#pragma unroll
                    for (int r = 0; r < 4; ++r) {
                        float pv = EXP2F(sf[st][r] * SCL);
                        if (st * 16 + l16 > t0 + w * 16 + q * 4 + r) pv = 0.f;
                        l_r[r] += pv;
                        Pb[0][w * 16 + q * 4 + r][st * 16 + l16] = f2bf(pv);
                    }
            }
        }

        for (int ci = 0; ci < nch; ++ci) {
            __syncthreads();
            bf16x8 pf[4][2];
#pragma unroll
            for (int mt = 0; mt < 4; ++mt)
#pragma unroll
                for (int ks = 0; ks < 2; ++ks)
                    pf[mt][ks] = *(bf16x8*)&Pb[ci & 1][mt * 16 + l16][ks * 32 + q * 8];
            const int s0 = ci * 64;
#pragma unroll
            for (int nt = 0; nt < 4; ++nt)
#pragma unroll
                for (int ks = 0; ks < 2; ++ks) {
                    bf16x8 vf = *(const bf16x8*)(ztb +
                        (size_t)(chb + nt * 16 + l16) * 1024 + s0 + ks * 32 + q * 8);
#pragma unroll
                    for (int mt = 0; mt < 4; ++mt)
                        acc[mt][nt] = MFMA16(pf[mt][ks], vf, acc[mt][nt]);
                }
            if (w < 4 && ci + 1 < nch) {
                const int cc = ci + 1, s0c = cc * 64, par = cc & 1;
                f32x4 sf[4];
#pragma unroll
                for (int st = 0; st < 4; ++st) sf[st] = (f32x4){0.f, 0.f, 0.f, 0.f};
#pragma unroll
                for (int st = 0; st < 4; ++st)
#pragma unroll
                    for (int ks = 0; ks < 2; ++ks) {
                        bf16x8 kf = *(const bf16x8*)(xbb +
                            (size_t)(s0c + st * 16 + l16) * 1024 + h * 64 + ks * 32 + q * 8);
                        sf[st] = MFMA16(qf[ks], kf, sf[st]);
                    }
#pragma unroll
                for (int st = 0; st < 4; ++st)
#pragma unroll
                    for (int r = 0; r < 4; ++r) {
                        float pv = EXP2F(sf[st][r] * SCL);
                        if (s0c + st * 16 + l16 > t0 + w * 16 + q * 4 + r) pv = 0.f;
                        l_r[r] += pv;
                        Pb[par][w * 16 + q * 4 + r][st * 16 + l16] = f2bf(pv);
                    }
            }
        }

        if (w < 4) {
#pragma unroll
            for (int r = 0; r < 4; ++r) {
                l_r[r] += __shfl_xor(l_r[r], 1);
                l_r[r] += __shfl_xor(l_r[r], 2);
                l_r[r] += __shfl_xor(l_r[r], 4);
                l_r[r] += __shfl_xor(l_r[r], 8);
            }
            if (l16 == 0) {
#pragma unroll
                for (int r = 0; r < 4; ++r) row_l[w * 16 + q * 4 + r] = l_r[r];
            }
        }
        __syncthreads();

#pragma unroll
        for (int mt = 0; mt < 4; ++mt) {
            float i0 = 1.f / row_l[mt * 16 + q * 4 + 0];
            float i1 = 1.f / row_l[mt * 16 + q * 4 + 1];
            float i2 = 1.f / row_l[mt * 16 + q * 4 + 2];
            float i3 = 1.f / row_l[mt * 16 + q * 4 + 3];
#pragma unroll
            for (int nt = 0; nt < 4; ++nt) {
                size_t base = (size_t)(b * 1024 + t0 + mt * 16 + q * 4) * 1024 +
                              chb + nt * 16 + l16;
                atomicAdd(out + base,        acc[mt][nt][0] * i0);
                atomicAdd(out + base + 1024, acc[mt][nt][1] * i1);
                atomicAdd(out + base + 2048, acc[mt][nt][2] * i2);
                atomicAdd(out + base + 3072, acc[mt][nt][3] * i3);
            }
        }
    }
}

// ---------------------------------------------------------------------------
extern "C" void kernel_launch(void* const* d_in, const int* in_sizes, int n_in,
                              void* d_out, int out_size, void* d_ws, size_t ws_size,
                              hipStream_t stream) {
    const float* x = (const float*)d_in[0];
    // d_in[1] (mask) recomputed analytically.
    const float* W = (const float*)d_in[2];
    float* out = (float*)d_out;

    const size_t MB = 1024 * 1024;
    short* xb  = (short*)d_ws;                         // [0,   4 MiB)
    short* ZT2 = (short*)d_ws + 2 * MB;                // [4,  68 MiB)  16384x2048
    short* P   = (short*)d_ws + 34 * MB;               // [68, 132 MiB) 32x1024x1024
    short* Wt  = P;                                    // overlaps P (used first)

    (void)hipMemsetAsync(d_out, 0, (size_t)B_ * T_ * C_ * sizeof(float), stream);
    cvt_x<<<(B_ * T_ * C_) / (256 * 8), 256, 0, stream>>>(x, xb);

    if (ws_size >= 132 * MB) {
        cvt_w<<<16 * 16 * 16, 256, 0, stream>>>(W, Wt);
        zgemm4<<<128 * 16, 256, 0, stream>>>(xb, Wt, ZT2);   // consumes Wt
        pgen<<<512, 256, 0, stream>>>(xb, P);                // overwrites Wt region
        pzgemm<<<512, 256, 0, stream>>>(P, ZT2, out);
    } else {
        short* ZT = ZT2;   // [b][h][n][s] layout, 64 MiB
        zgemm_sm<<<H_ * 8 * 8, 256, 0, stream>>>(xb, W, ZT);
        attn_fb<<<512, 512, 0, stream>>>(xb, ZT, out);
    }
}

// Round 7
// 442.047 us; speedup vs baseline: 1.0456x; 1.0456x over previous
//
#include <hip/hip_runtime.h>
#include <hip/hip_bf16.h>

#define B_ 2
#define T_ 1024
#define C_ 1024
#define H_ 16

typedef short bf16x8 __attribute__((ext_vector_type(8)));
typedef float f32x4 __attribute__((ext_vector_type(4)));

#define MFMA16(a, b, c) __builtin_amdgcn_mfma_f32_16x16x32_bf16(a, b, c, 0, 0, 0)
#define EXP2F(x) __builtin_amdgcn_exp2f(x)
#define SCL 0.36067376f   // 0.25 * log2(e): exp(s/4) = 2^(s*SCL)

__device__ inline short f2bf(float x) {
    union { __hip_bfloat16 h; short s; } u;
    u.h = __float2bfloat16(x);
    return u.s;
}

__device__ inline void gl_lds16(const void* g, void* l) {
    __builtin_amdgcn_global_load_lds(
        (const __attribute__((address_space(1))) unsigned int*)g,
        (__attribute__((address_space(3))) unsigned int*)l, 16, 0, 0);
}

// ---------------------------------------------------------------------------
// x (fp32) -> xb (bf16), flat. 2M elems, 8/thread.
// ---------------------------------------------------------------------------
__global__ __launch_bounds__(256) void cvt_x(const float* __restrict__ x,
                                             short* __restrict__ xb) {
    int idx = (blockIdx.x * 256 + threadIdx.x) * 8;
    float4 a = *(const float4*)(x + idx);
    float4 b = *(const float4*)(x + idx + 4);
    bf16x8 v;
    v[0] = f2bf(a.x); v[1] = f2bf(a.y); v[2] = f2bf(a.z); v[3] = f2bf(a.w);
    v[4] = f2bf(b.x); v[5] = f2bf(b.y); v[6] = f2bf(b.z); v[7] = f2bf(b.w);
    *(bf16x8*)(xb + idx) = v;
}

// ---------------------------------------------------------------------------
// Wt[(h*1024+n)][c] = bf16(W[h*1024+c][n]) — one-time transpose+convert.
// ---------------------------------------------------------------------------
__global__ __launch_bounds__(256) void cvt_w(const float* __restrict__ W,
                                             short* __restrict__ Wt) {
    __shared__ float T[64][65];
    const int bid = blockIdx.x;
    const int nb = bid & 15, cb = (bid >> 4) & 15, h = bid >> 8;
    const int t = threadIdx.x;
    const int c0 = cb * 64, n0 = nb * 64;
    const float* src = W + (size_t)(h * 1024 + c0) * 1024 + n0;
    {
        const int cl = t >> 4, nl = (t & 15) * 4;
#pragma unroll
        for (int r = 0; r < 4; ++r) {
            float4 v = *(const float4*)(src + (size_t)(cl + r * 16) * 1024 + nl);
            T[cl + r * 16][nl + 0] = v.x;
            T[cl + r * 16][nl + 1] = v.y;
            T[cl + r * 16][nl + 2] = v.z;
            T[cl + r * 16][nl + 3] = v.w;
        }
    }
    __syncthreads();
    {
        short* dst = Wt + (size_t)(h * 1024 + n0) * 1024 + c0;
        const int nl = t >> 3, cl8 = (t & 7) * 8;
#pragma unroll
        for (int r = 0; r < 2; ++r) {
            const int n = nl + r * 32;
            bf16x8 o;
#pragma unroll
            for (int j = 0; j < 8; ++j) o[j] = f2bf(T[cl8 + j][n]);
            *(bf16x8*)(dst + (size_t)n * 1024 + cl8) = o;
        }
    }
}

// ---------------------------------------------------------------------------
// zgemm4 v2: ZT2[m][sg] = sum_c Wt[m][c]*xb[sg][c]. 128x128 tile, BK=64
// (32 MFMA/wave between barriers), 256 thr. bid = mt + 128*nt: same-A (mt)
// blocks are bid≡ mod 8 -> one XCD's L2 holds each Wt slice (A-locality).
// ---------------------------------------------------------------------------
__global__ __launch_bounds__(256) void zgemm4(const short* __restrict__ xb,
                                              const short* __restrict__ Wt,
                                              short* __restrict__ ZT2) {
    __shared__ short SMEM[16384];     // 32 KiB: Al 16K | Bl 16K
    short* Al = SMEM;                 // [8 kg][128 m][8]
    short* Bl = SMEM + 8192;          // [8 kg][128 s][8]

    const int bid = blockIdx.x;
    const int mt = bid & 127, nt = bid >> 7;
    const int m0 = mt * 128, n0 = nt * 128;
    const int t = threadIdx.x;
    const int lane = t & 63, q = lane >> 4, l16 = lane & 15;
    const int w = t >> 6, wm = (w & 1) * 64, wn = (w >> 1) * 64;

    const short* Ab = Wt + (size_t)m0 * 1024;
    const short* Bb = xb + (size_t)n0 * 1024;
    char* al0 = (char*)Al + (size_t)t * 16;
    char* bl0 = (char*)Bl + (size_t)t * 16;

    f32x4 acc[4][4];
#pragma unroll
    for (int i = 0; i < 4; ++i)
#pragma unroll
        for (int j = 0; j < 4; ++j) acc[i][j] = (f32x4){0.f, 0.f, 0.f, 0.f};

    for (int k0 = 0; k0 < 1024; k0 += 64) {
        __syncthreads();
#pragma unroll
        for (int rd = 0; rd < 4; ++rd) {
            int idx = rd * 256 + t;
            gl_lds16(Ab + (size_t)(idx & 127) * 1024 + k0 + (idx >> 7) * 8,
                     al0 + rd * 4096);
            gl_lds16(Bb + (size_t)(idx & 127) * 1024 + k0 + (idx >> 7) * 8,
                     bl0 + rd * 4096);
        }
        __syncthreads();
#pragma unroll
        for (int kk = 0; kk < 2; ++kk) {
            const int kg = kk * 4 + q;
            bf16x8 af[4], bfr[4];
#pragma unroll
            for (int i = 0; i < 4; ++i)
                af[i] = *(bf16x8*)&Al[(kg * 128 + wm + i * 16 + l16) * 8];
#pragma unroll
            for (int j = 0; j < 4; ++j)
                bfr[j] = *(bf16x8*)&Bl[(kg * 128 + wn + j * 16 + l16) * 8];
#pragma unroll
            for (int i = 0; i < 4; ++i)
#pragma unroll
                for (int j = 0; j < 4; ++j)
                    acc[i][j] = MFMA16(af[i], bfr[j], acc[i][j]);
        }
    }

    // Epilogue: per-wave LDS transpose -> 16B coalesced stores into ZT2.
    __syncthreads();
    short* Cw = SMEM + w * 2304;      // [32][72] per wave
    const int lr2 = lane >> 1, ch = lane & 1;
#pragma unroll
    for (int p2 = 0; p2 < 2; ++p2) {
#pragma unroll
        for (int i2 = 0; i2 < 2; ++i2) {
            const int i = p2 * 2 + i2, row = i2 * 16 + q * 4;
#pragma unroll
            for (int j = 0; j < 4; ++j)
#pragma unroll
                for (int r = 0; r < 4; ++r)
                    Cw[(row + r) * 72 + j * 16 + l16] = f2bf(acc[i][j][r]);
        }
        const size_t m_abs = m0 + wm + p2 * 32 + lr2;
#pragma unroll
        for (int u = 0; u < 4; ++u) {
            bf16x8 v = *(bf16x8*)&Cw[lr2 * 72 + ch * 32 + u * 8];
            *(bf16x8*)(ZT2 + m_abs * 2048 + n0 + wn + ch * 32 + u * 8) = v;
        }
    }
}

// ---------------------------------------------------------------------------
// pgen: P[b][h][t][s] = exp(score/4)/l_row, causal (static-max softmax).
// Two-pass recompute. Even tiles zero-fill the next 64-chunk so pzgemm's
// 128-row tiles never read uninitialized P.
// ---------------------------------------------------------------------------
__global__ __launch_bounds__(256) void pgen(const short* __restrict__ xb,
                                            short* __restrict__ P) {
    __shared__ short Pw[4][16][72];

    const int bid = blockIdx.x;
    const int tb = bid & 15, h = (bid >> 4) & 15, b = bid >> 8;
    const int t0 = tb * 64;
    const int t = threadIdx.x;
    const int lane = t & 63, q = lane >> 4, l16 = lane & 15;
    const int w = t >> 6;
    const short* xbb = xb + ((size_t)b << 20);
    short* Pb = P + (((size_t)(b * 16 + h)) << 20);

    bf16x8 qf[2];
#pragma unroll
    for (int ks = 0; ks < 2; ++ks)
        qf[ks] = *(const bf16x8*)(xbb + (size_t)(t0 + w * 16 + l16) * 1024 +
                                  h * 64 + ks * 32 + q * 8);

    float l_r[4] = {0.f, 0.f, 0.f, 0.f};
    for (int ci = 0; ci <= tb; ++ci) {
        const int s0 = ci * 64;
        f32x4 sf[4];
#pragma unroll
        for (int st = 0; st < 4; ++st) sf[st] = (f32x4){0.f, 0.f, 0.f, 0.f};
#pragma unroll
        for (int st = 0; st < 4; ++st)
#pragma unroll
            for (int ks = 0; ks < 2; ++ks) {
                bf16x8 kf = *(const bf16x8*)(xbb +
                    (size_t)(s0 + st * 16 + l16) * 1024 + h * 64 + ks * 32 + q * 8);
                sf[st] = MFMA16(qf[ks], kf, sf[st]);
            }
#pragma unroll
        for (int st = 0; st < 4; ++st)
#pragma unroll
            for (int r = 0; r < 4; ++r) {
                float pv = EXP2F(sf[st][r] * SCL);
                if (s0 + st * 16 + l16 > t0 + w * 16 + q * 4 + r) pv = 0.f;
                l_r[r] += pv;
            }
    }
    float inv[4];
#pragma unroll
    for (int r = 0; r < 4; ++r) {
        l_r[r] += __shfl_xor(l_r[r], 1);
        l_r[r] += __shfl_xor(l_r[r], 2);
        l_r[r] += __shfl_xor(l_r[r], 4);
        l_r[r] += __shfl_xor(l_r[r], 8);
        inv[r] = 1.f / l_r[r];
    }

    for (int ci = 0; ci <= tb; ++ci) {
        const int s0 = ci * 64;
        f32x4 sf[4];
#pragma unroll
        for (int st = 0; st < 4; ++st) sf[st] = (f32x4){0.f, 0.f, 0.f, 0.f};
#pragma unroll
        for (int st = 0; st < 4; ++st)
#pragma unroll
            for (int ks = 0; ks < 2; ++ks) {
                bf16x8 kf = *(const bf16x8*)(xbb +
                    (size_t)(s0 + st * 16 + l16) * 1024 + h * 64 + ks * 32 + q * 8);
                sf[st] = MFMA16(qf[ks], kf, sf[st]);
            }
#pragma unroll
        for (int st = 0; st < 4; ++st)
#pragma unroll
            for (int r = 0; r < 4; ++r) {
                float pv = EXP2F(sf[st][r] * SCL) * inv[r];
                if (s0 + st * 16 + l16 > t0 + w * 16 + q * 4 + r) pv = 0.f;
                Pw[w][q * 4 + r][st * 16 + l16] = f2bf(pv);
            }
        short* prow = Pb + (size_t)(t0 + w * 16 + l16) * 1024 + s0;
        *(bf16x8*)(prow + q * 8)      = *(bf16x8*)&Pw[w][l16][q * 8];
        *(bf16x8*)(prow + 32 + q * 8) = *(bf16x8*)&Pw[w][l16][32 + q * 8];
    }
    if (!(tb & 1)) {
        bf16x8 z = {0, 0, 0, 0, 0, 0, 0, 0};
        short* prow = Pb + (size_t)(t0 + w * 16 + l16) * 1024 + (tb + 1) * 64;
        *(bf16x8*)(prow + q * 8)      = z;
        *(bf16x8*)(prow + 32 + q * 8) = z;
    }
}

// ---------------------------------------------------------------------------
// pzgemm v2: out[b*1024+t][n] += sum_h sum_s P[b][h][t][s]*ZT2[(h,n)][(b,s)].
// 128x128 tile, BK=64, 8-way head split (2 heads/block), tile-PAIR (tt,7-tt)
// per block -> constant K-work 2*1152 regardless of pair. bid = low6 + 64*nt:
// same-A (P-slice) blocks are bid≡ mod 8 -> single-XCD P fetch.
// fp32 atomic epilogue into pre-zeroed out.
// ---------------------------------------------------------------------------
__global__ __launch_bounds__(256) void pzgemm(const short* __restrict__ P,
                                              const short* __restrict__ ZT2,
                                              float* __restrict__ out) {
    __shared__ short SMEM[16384];
    short* Al = SMEM;                 // [8 kg][128 t][8]
    short* Bl = SMEM + 8192;          // [8 kg][128 n][8]

    const int bid = blockIdx.x;
    const int nt = bid >> 6;
    const int low = bid & 63;
    const int pair = low & 3, hs = (low >> 2) & 7, b = low >> 5;
    const int n0 = nt * 128;
    const int t = threadIdx.x;
    const int lane = t & 63, q = lane >> 4, l16 = lane & 15;
    const int w = t >> 6, wm = (w & 1) * 64, wn = (w >> 1) * 64;
    char* al0 = (char*)Al + (size_t)t * 16;
    char* bl0 = (char*)Bl + (size_t)t * 16;

#pragma unroll
    for (int ti = 0; ti < 2; ++ti) {
        const int tt = ti ? pair : 7 - pair;      // big tile first
        const int t0 = tt * 128, send = t0 + 128; // causal K bound

        f32x4 acc[4][4];
#pragma unroll
        for (int i = 0; i < 4; ++i)
#pragma unroll
            for (int j = 0; j < 4; ++j) acc[i][j] = (f32x4){0.f, 0.f, 0.f, 0.f};

        for (int hh = 0; hh < 2; ++hh) {
            const int h = hs * 2 + hh;
            const short* Ab = P + (((size_t)(b * 16 + h)) << 20) + (size_t)t0 * 1024;
            const short* Bb = ZT2 + (size_t)(h * 1024 + n0) * 2048 + b * 1024;
            for (int s0 = 0; s0 < send; s0 += 64) {
                __syncthreads();
#pragma unroll
                for (int rd = 0; rd < 4; ++rd) {
                    int idx = rd * 256 + t;
                    gl_lds16(Ab + (size_t)(idx & 127) * 1024 + s0 + (idx >> 7) * 8,
                             al0 + rd * 4096);
                    gl_lds16(Bb + (size_t)(idx & 127) * 2048 + s0 + (idx >> 7) * 8,
                             bl0 + rd * 4096);
                }
                __syncthreads();
#pragma unroll
                for (int kk = 0; kk < 2; ++kk) {
                    const int kg = kk * 4 + q;
                    bf16x8 af[4], bfr[4];
#pragma unroll
                    for (int i = 0; i < 4; ++i)
                        af[i] = *(bf16x8*)&Al[(kg * 128 + wm + i * 16 + l16) * 8];
#pragma unroll
                    for (int j = 0; j < 4; ++j)
                        bfr[j] = *(bf16x8*)&Bl[(kg * 128 + wn + j * 16 + l16) * 8];
#pragma unroll
                    for (int i = 0; i < 4; ++i)
#pragma unroll
                        for (int j = 0; j < 4; ++j)
                            acc[i][j] = MFMA16(af[i], bfr[j], acc[i][j]);
                }
            }
        }

        // Head-group partial sums -> fp32 atomics (out pre-zeroed).
#pragma unroll
        for (int i = 0; i < 4; ++i)
#pragma unroll
            for (int j = 0; j < 4; ++j) {
                size_t base = (size_t)(b * 1024 + t0 + wm + i * 16 + q * 4) * 1024 +
                              n0 + wn + j * 16 + l16;
                atomicAdd(out + base,        acc[i][j][0]);
                atomicAdd(out + base + 1024, acc[i][j][1]);
                atomicAdd(out + base + 2048, acc[i][j][2]);
                atomicAdd(out + base + 3072, acc[i][j][3]);
            }
    }
}

// ===========================================================================
// Fallback path (ws < 132 MiB): round-5 proven kernels.
// ===========================================================================
#define ZPAD 40

__global__ __launch_bounds__(256, 2) void zgemm_sm(const short* __restrict__ xb,
                                                   const float* __restrict__ W,
                                                   short* __restrict__ ZT) {
    __shared__ short Wts[128 * ZPAD];
    __shared__ short Xs[2][128 * ZPAD];

    const int tid = threadIdx.x;
    const int bs = blockIdx.x & 7;
    const int bn = (blockIdx.x >> 3) & 7;
    const int h  = blockIdx.x >> 6;
    const int s0 = bs * 128, n0 = bn * 128;
    const int lane = tid & 63, q = lane >> 4, l16 = lane & 15;
    const int w = tid >> 6, bw = w >> 1, sh = w & 1;

    f32x4 acc[8][4];
#pragma unroll
    for (int i = 0; i < 8; ++i)
#pragma unroll
        for (int j = 0; j < 4; ++j) acc[i][j] = (f32x4){0.f, 0.f, 0.f, 0.f};

    for (int k0 = 0; k0 < 1024; k0 += 32) {
        __syncthreads();
#pragma unroll
        for (int r = 0; r < 2; ++r) {
            const int c2 = ((tid >> 5) << 1) + (r << 4);
            const float* w0p = W + (size_t)(h * 1024 + k0 + c2) * 1024 + n0;
            const float* w1p = w0p + 1024;
#pragma unroll
            for (int i = 0; i < 4; ++i) {
                const int n = (tid & 31) + (i << 5);
                float wa = w0p[n], wb = w1p[n];
                unsigned u = (unsigned)(unsigned short)f2bf(wa) |
                             ((unsigned)(unsigned short)f2bf(wb) << 16);
                *(unsigned*)&Wts[n * ZPAD + c2] = u;
            }
        }
#pragma unroll
        for (int i = 0; i < 4; ++i) {
            const int id = tid + (i << 8);
            const int b2 = id >> 9, s = (id >> 2) & 127, cg = id & 3;
            bf16x8 v = *(const bf16x8*)(xb + (size_t)b2 * (T_ * C_) +
                                        (size_t)(s0 + s) * 1024 + k0 + cg * 8);
            *(bf16x8*)&Xs[b2][s * ZPAD + cg * 8] = v;
        }
        __syncthreads();

        bf16x8 af[8], bfr[4];
#pragma unroll
        for (int ntv = 0; ntv < 8; ++ntv)
            af[ntv] = *(bf16x8*)&Wts[(ntv * 16 + l16) * ZPAD + q * 8];
#pragma unroll
        for (int st = 0; st < 4; ++st)
            bfr[st] = *(bf16x8*)&Xs[bw][(sh * 64 + st * 16 + l16) * ZPAD + q * 8];
#pragma unroll
        for (int ntv = 0; ntv < 8; ++ntv)
#pragma unroll
            for (int st = 0; st < 4; ++st)
                acc[ntv][st] = MFMA16(af[ntv], bfr[st], acc[ntv][st]);
    }

    short* zb = ZT + (size_t)(bw * 16 + h) * (1024 * 1024);
#pragma unroll
    for (int ntv = 0; ntv < 8; ++ntv)
#pragma unroll
        for (int st = 0; st < 4; ++st)
#pragma unroll
            for (int r = 0; r < 4; ++r) {
                int n_abs = n0 + ntv * 16 + q * 4 + r;
                int s_abs = s0 + sh * 64 + st * 16 + l16;
                zb[(size_t)n_abs * 1024 + s_abs] = f2bf(acc[ntv][st][r]);
            }
}

__global__ __launch_bounds__(512, 4) void attn_fb(const short* __restrict__ xb,
                                                  const short* __restrict__ ZT,
                                                  float* __restrict__ out) {
    __shared__ short Pb[2][64][72];
    __shared__ float row_l[64];

    const int tid = threadIdx.x;
    const int bh = blockIdx.x & 31;
    const int chhalf = (blockIdx.x >> 5) & 1;
    const int p = blockIdx.x >> 6;
    const int b = bh >> 4, h = bh & 15;
    const int lane = tid & 63, q = lane >> 4, l16 = lane & 15;
    const int w = tid >> 6;
    const int chb = chhalf * 512 + w * 64;
    const short* xbb = xb + ((size_t)b << 20);
    const short* ztb = ZT + ((size_t)(b * 16 + h) << 20);

    const int tiles[2] = { p, 15 - p };
    for (int ti = 0; ti < 2; ++ti) {
        const int tb = tiles[ti], t0 = tb * 64, nch = tb + 1;

        f32x4 acc[4][4];
#pragma unroll
        for (int mt = 0; mt < 4; ++mt)
#pragma unroll
            for (int nt = 0; nt < 4; ++nt) acc[mt][nt] = (f32x4){0.f, 0.f, 0.f, 0.f};
        float l_r[4] = {0.f, 0.f, 0.f, 0.f};

        __syncthreads();

        bf16x8 qf[2];
        if (w < 4) {
#pragma unroll
            for (int ks = 0; ks < 2; ++ks)
                qf[ks] = *(const bf16x8*)(xbb + (size_t)(t0 + w * 16 + l16) * 1024 +
                                          h * 64 + ks * 32 + q * 8);
            {
                f32x4 sf[4];
#pragma unroll
                for (int st = 0; st < 4; ++st) sf[st] = (f32x4){0.f, 0.f, 0.f, 0.f};
#pragma unroll
                for (int st = 0; st < 4; ++st)
#pragma unroll
                    for (int ks = 0; ks < 2; ++ks) {
                        bf16x8 kf = *(const bf16x8*)(xbb +
                            (size_t)(st * 16 + l16) * 1024 + h * 64 + ks * 32 + q * 8);
                        sf[st] = MFMA16(qf[ks], kf, sf[st]);
                    }
#pragma unroll
                for (int st = 0; st < 4; ++st)
#pragma unroll
                    for (int r = 0; r < 4; ++r) {
                        float pv = EXP2F(sf[st][r] * SCL);
                        if (st * 16 + l16 > t0 + w * 16 + q * 4 + r) pv = 0.f;
                        l_r[r] += pv;
                        Pb[0][w * 16 + q * 4 + r][st * 16 + l16] = f2bf(pv);
                    }
            }
        }

        for (int ci = 0; ci < nch; ++ci) {
            __syncthreads();
            bf16x8 pf[4][2];
#pragma unroll
            for (int mt = 0; mt < 4; ++mt)
#pragma unroll
                for (int ks = 0; ks < 2; ++ks)
                    pf[mt][ks] = *(bf16x8*)&Pb[ci & 1][mt * 16 + l16][ks * 32 + q * 8];
            const int s0 = ci * 64;
#pragma unroll
            for (int nt = 0; nt < 4; ++nt)
#pragma unroll
                for (int ks = 0; ks < 2; ++ks) {
                    bf16x8 vf = *(const bf16x8*)(ztb +
                        (size_t)(chb + nt * 16 + l16) * 1024 + s0 + ks * 32 + q * 8);
#pragma unroll
                    for (int mt = 0; mt < 4; ++mt)
                        acc[mt][nt] = MFMA16(pf[mt][ks], vf, acc[mt][nt]);
                }
            if (w < 4 && ci + 1 < nch) {
                const int cc = ci + 1, s0c = cc * 64, par = cc & 1;
                f32x4 sf[4];
#pragma unroll
                for (int st = 0; st < 4; ++st) sf[st] = (f32x4){0.f, 0.f, 0.f, 0.f};
#pragma unroll
                for (int st = 0; st < 4; ++st)
#pragma unroll
                    for (int ks = 0; ks < 2; ++ks) {
                        bf16x8 kf = *(const bf16x8*)(xbb +
                            (size_t)(s0c + st * 16 + l16) * 1024 + h * 64 + ks * 32 + q * 8);
                        sf[st] = MFMA16(qf[ks], kf, sf[st]);
                    }
#pragma unroll
                for (int st = 0; st < 4; ++st)
#pragma unroll
                    for (int r = 0; r < 4; ++r) {
                        float pv = EXP2F(sf[st][r] * SCL);
                        if (s0c + st * 16 + l16 > t0 + w * 16 + q * 4 + r) pv = 0.f;
                        l_r[r] += pv;
                        Pb[par][w * 16 + q * 4 + r][st * 16 + l16] = f2bf(pv);
                    }
            }
        }

        if (w < 4) {
#pragma unroll
            for (int r = 0; r < 4; ++r) {
                l_r[r] += __shfl_xor(l_r[r], 1);
                l_r[r] += __shfl_xor(l_r[r], 2);
                l_r[r] += __shfl_xor(l_r[r], 4);
                l_r[r] += __shfl_xor(l_r[r], 8);
            }
            if (l16 == 0) {
#pragma unroll
                for (int r = 0; r < 4; ++r) row_l[w * 16 + q * 4 + r] = l_r[r];
            }
        }
        __syncthreads();

#pragma unroll
        for (int mt = 0; mt < 4; ++mt) {
            float i0 = 1.f / row_l[mt * 16 + q * 4 + 0];
            float i1 = 1.f / row_l[mt * 16 + q * 4 + 1];
            float i2 = 1.f / row_l[mt * 16 + q * 4 + 2];
            float i3 = 1.f / row_l[mt * 16 + q * 4 + 3];
#pragma unroll
            for (int nt = 0; nt < 4; ++nt) {
                size_t base = (size_t)(b * 1024 + t0 + mt * 16 + q * 4) * 1024 +
                              chb + nt * 16 + l16;
                atomicAdd(out + base,        acc[mt][nt][0] * i0);
                atomicAdd(out + base + 1024, acc[mt][nt][1] * i1);
                atomicAdd(out + base + 2048, acc[mt][nt][2] * i2);
                atomicAdd(out + base + 3072, acc[mt][nt][3] * i3);
            }
        }
    }
}

// ---------------------------------------------------------------------------
extern "C" void kernel_launch(void* const* d_in, const int* in_sizes, int n_in,
                              void* d_out, int out_size, void* d_ws, size_t ws_size,
                              hipStream_t stream) {
    const float* x = (const float*)d_in[0];
    // d_in[1] (mask) recomputed analytically.
    const float* W = (const float*)d_in[2];
    float* out = (float*)d_out;

    const size_t MB = 1024 * 1024;
    short* xb  = (short*)d_ws;                         // [0,   4 MiB)
    short* ZT2 = (short*)d_ws + 2 * MB;                // [4,  68 MiB)  16384x2048
    short* P   = (short*)d_ws + 34 * MB;               // [68, 132 MiB) 32x1024x1024
    short* Wt  = P;                                    // overlaps P (used first)

    (void)hipMemsetAsync(d_out, 0, (size_t)B_ * T_ * C_ * sizeof(float), stream);
    cvt_x<<<(B_ * T_ * C_) / (256 * 8), 256, 0, stream>>>(x, xb);

    if (ws_size >= 132 * MB) {
        cvt_w<<<16 * 16 * 16, 256, 0, stream>>>(W, Wt);
        zgemm4<<<128 * 16, 256, 0, stream>>>(xb, Wt, ZT2);   // consumes Wt
        pgen<<<512, 256, 0, stream>>>(xb, P);                // overwrites Wt region
        pzgemm<<<512, 256, 0, stream>>>(P, ZT2, out);
    } else {
        short* ZT = ZT2;   // [b][h][n][s] layout, 64 MiB
        zgemm_sm<<<H_ * 8 * 8, 256, 0, stream>>>(xb, W, ZT);
        attn_fb<<<512, 512, 0, stream>>>(xb, ZT, out);
    }
}

// Round 8
// 416.369 us; speedup vs baseline: 1.1101x; 1.0617x over previous
//
#include <hip/hip_runtime.h>
#include <hip/hip_bf16.h>

#define B_ 2
#define T_ 1024
#define C_ 1024
#define H_ 16

typedef short bf16x8 __attribute__((ext_vector_type(8)));
typedef float f32x4 __attribute__((ext_vector_type(4)));

#define MFMA16(a, b, c) __builtin_amdgcn_mfma_f32_16x16x32_bf16(a, b, c, 0, 0, 0)
#define EXP2F(x) __builtin_amdgcn_exp2f(x)
#define SCL 0.36067376f   // 0.25 * log2(e): exp(s/4) = 2^(s*SCL)

__device__ inline short f2bf(float x) {
    union { __hip_bfloat16 h; short s; } u;
    u.h = __float2bfloat16(x);
    return u.s;
}

__device__ inline void gl_lds16(const void* g, void* l) {
    __builtin_amdgcn_global_load_lds(
        (const __attribute__((address_space(1))) unsigned int*)g,
        (__attribute__((address_space(3))) unsigned int*)l, 16, 0, 0);
}

// ---------------------------------------------------------------------------
// x (fp32) -> xb (bf16), flat. 2M elems, 8/thread.
// ---------------------------------------------------------------------------
__global__ __launch_bounds__(256) void cvt_x(const float* __restrict__ x,
                                             short* __restrict__ xb) {
    int idx = (blockIdx.x * 256 + threadIdx.x) * 8;
    float4 a = *(const float4*)(x + idx);
    float4 b = *(const float4*)(x + idx + 4);
    bf16x8 v;
    v[0] = f2bf(a.x); v[1] = f2bf(a.y); v[2] = f2bf(a.z); v[3] = f2bf(a.w);
    v[4] = f2bf(b.x); v[5] = f2bf(b.y); v[6] = f2bf(b.z); v[7] = f2bf(b.w);
    *(bf16x8*)(xb + idx) = v;
}

// ---------------------------------------------------------------------------
// Wt[(h*1024+n)][c] = bf16(W[h*1024+c][n]) — one-time transpose+convert.
// ---------------------------------------------------------------------------
__global__ __launch_bounds__(256) void cvt_w(const float* __restrict__ W,
                                             short* __restrict__ Wt) {
    __shared__ float T[64][65];
    const int bid = blockIdx.x;
    const int nb = bid & 15, cb = (bid >> 4) & 15, h = bid >> 8;
    const int t = threadIdx.x;
    const int c0 = cb * 64, n0 = nb * 64;
    const float* src = W + (size_t)(h * 1024 + c0) * 1024 + n0;
    {
        const int cl = t >> 4, nl = (t & 15) * 4;
#pragma unroll
        for (int r = 0; r < 4; ++r) {
            float4 v = *(const float4*)(src + (size_t)(cl + r * 16) * 1024 + nl);
            T[cl + r * 16][nl + 0] = v.x;
            T[cl + r * 16][nl + 1] = v.y;
            T[cl + r * 16][nl + 2] = v.z;
            T[cl + r * 16][nl + 3] = v.w;
        }
    }
    __syncthreads();
    {
        short* dst = Wt + (size_t)(h * 1024 + n0) * 1024 + c0;
        const int nl = t >> 3, cl8 = (t & 7) * 8;
#pragma unroll
        for (int r = 0; r < 2; ++r) {
            const int n = nl + r * 32;
            bf16x8 o;
#pragma unroll
            for (int j = 0; j < 8; ++j) o[j] = f2bf(T[cl8 + j][n]);
            *(bf16x8*)(dst + (size_t)n * 1024 + cl8) = o;
        }
    }
}

// ---------------------------------------------------------------------------
// zgemm4 (R6 params = best measured): ZT[b][h][n][s] = bf16((x_b@W_h)^T).
// 128x128 tile, BK=32, 256 thr, global_load_lds staging, LDS-transpose
// epilogue. bid = mt + 128*st: same-A (Wt slice) blocks ≡ mod 8 -> XCD L2
// A-locality (R7's FETCH win).
// ---------------------------------------------------------------------------
__global__ __launch_bounds__(256) void zgemm4(const short* __restrict__ xb,
                                              const short* __restrict__ Wt,
                                              short* __restrict__ ZT) {
    __shared__ short SMEM[9216];      // staging 8192 shorts; epilogue 9216
    short* Al = SMEM;                 // [4 kg][128 m][8]
    short* Bl = SMEM + 4096;          // [4 kg][128 s][8]

    const int bid = blockIdx.x;
    const int mt = bid & 127, st = bid >> 7;
    const int m0 = mt * 128, s0g = st * 128;   // m over 16384 (h,n); s over 2048
    const int t = threadIdx.x;
    const int lane = t & 63, q = lane >> 4, l16 = lane & 15;
    const int w = t >> 6, wm = (w & 1) * 64, wn = (w >> 1) * 64;

    const short* Ab = Wt + (size_t)m0 * 1024;
    const short* Bb = xb + (size_t)s0g * 1024;
    const int srow = t & 127, skg = t >> 7;
    char* al0 = (char*)Al + (size_t)t * 16;
    char* bl0 = (char*)Bl + (size_t)t * 16;

    f32x4 acc[4][4];
#pragma unroll
    for (int i = 0; i < 4; ++i)
#pragma unroll
        for (int j = 0; j < 4; ++j) acc[i][j] = (f32x4){0.f, 0.f, 0.f, 0.f};

    for (int k0 = 0; k0 < 1024; k0 += 32) {
        __syncthreads();
        gl_lds16(Ab + (size_t)srow * 1024 + k0 + skg * 8, al0);
        gl_lds16(Ab + (size_t)srow * 1024 + k0 + (skg + 2) * 8, al0 + 4096);
        gl_lds16(Bb + (size_t)srow * 1024 + k0 + skg * 8, bl0);
        gl_lds16(Bb + (size_t)srow * 1024 + k0 + (skg + 2) * 8, bl0 + 4096);
        __syncthreads();
        bf16x8 af[4], bfr[4];
#pragma unroll
        for (int i = 0; i < 4; ++i)
            af[i] = *(bf16x8*)&Al[(q * 128 + wm + i * 16 + l16) * 8];
#pragma unroll
        for (int j = 0; j < 4; ++j)
            bfr[j] = *(bf16x8*)&Bl[(q * 128 + wn + j * 16 + l16) * 8];
#pragma unroll
        for (int i = 0; i < 4; ++i)
#pragma unroll
            for (int j = 0; j < 4; ++j)
                acc[i][j] = MFMA16(af[i], bfr[j], acc[i][j]);
    }

    // Epilogue: per-wave LDS transpose -> 16B coalesced stores, ZT[b][h][n][s].
    __syncthreads();
    const int h = m0 >> 10, n_in0 = m0 & 1023;
    const int b = s0g >> 10, s_in0 = (s0g & 1023) + wn;
    short* zb = ZT + ((size_t)(b * 16 + h) << 20);
    short* Cw = SMEM + w * 2304;      // [32][72] per wave
    const int lr2 = lane >> 1, ch = lane & 1;
#pragma unroll
    for (int p2 = 0; p2 < 2; ++p2) {
#pragma unroll
        for (int i2 = 0; i2 < 2; ++i2) {
            const int i = p2 * 2 + i2, row = i2 * 16 + q * 4;
#pragma unroll
            for (int j = 0; j < 4; ++j)
#pragma unroll
                for (int r = 0; r < 4; ++r)
                    Cw[(row + r) * 72 + j * 16 + l16] = f2bf(acc[i][j][r]);
        }
        const int n_abs = n_in0 + wm + p2 * 32 + lr2;
#pragma unroll
        for (int u = 0; u < 4; ++u) {
            bf16x8 v = *(bf16x8*)&Cw[lr2 * 72 + ch * 32 + u * 8];
            *(bf16x8*)(zb + (size_t)n_abs * 1024 + s_in0 + ch * 32 + u * 8) = v;
        }
    }
}

// ---------------------------------------------------------------------------
// attn (R3 structure + static softmax, ONE 64-row tile per block):
// Block = (b, h, tile tb of 64 t-rows); 512 blocks (2/CU), heavy tiles first.
// 8 waves: all do PV on disjoint 128-ch slices; waves 0-3 also do QK+exp for
// row-group w. Double-buffered P in LDS, 1 barrier/chunk. Static-max softmax
// (logits = s/4 bounded -> fp32 exp safe; 1/l applied at epilogue).
// out += (1/l) * P@Z via fp32 atomics (out pre-zeroed).
// ---------------------------------------------------------------------------
__global__ __launch_bounds__(512, 2) void attn(const short* __restrict__ xb,
                                               const short* __restrict__ ZT,
                                               float* __restrict__ out) {
    __shared__ short Pb[2][64][72];     // 18 KiB, double-buffered
    __shared__ float row_l[64];

    const int tid = threadIdx.x;
    const int bh = blockIdx.x & 31;                // XCD-pin
    const int tb = 15 - (blockIdx.x >> 5);         // heavy (large tb) first
    const int b = bh >> 4, h = bh & 15;
    const int lane = tid & 63, q = lane >> 4, l16 = lane & 15;
    const int w = tid >> 6, nw = w * 128;          // PV channel base
    const int t0 = tb * 64, nch = tb + 1;
    const short* xbb = xb + ((size_t)b << 20);
    const short* ztb = ZT + ((size_t)(b * 16 + h) << 20);

    f32x4 acc[4][8];
#pragma unroll
    for (int mt = 0; mt < 4; ++mt)
#pragma unroll
        for (int nt = 0; nt < 8; ++nt) acc[mt][nt] = (f32x4){0.f, 0.f, 0.f, 0.f};
    float l_r[4] = {0.f, 0.f, 0.f, 0.f};

    bf16x8 qf[2];
    if (w < 4) {
#pragma unroll
        for (int ks = 0; ks < 2; ++ks)
            qf[ks] = *(const bf16x8*)(xbb + (size_t)(t0 + w * 16 + l16) * 1024 +
                                      h * 64 + ks * 32 + q * 8);
        // ---- QK chunk 0 into Pb[0] ----
        f32x4 sf[4];
#pragma unroll
        for (int st = 0; st < 4; ++st) sf[st] = (f32x4){0.f, 0.f, 0.f, 0.f};
#pragma unroll
        for (int st = 0; st < 4; ++st)
#pragma unroll
            for (int ks = 0; ks < 2; ++ks) {
                bf16x8 kf = *(const bf16x8*)(xbb +
                    (size_t)(st * 16 + l16) * 1024 + h * 64 + ks * 32 + q * 8);
                sf[st] = MFMA16(qf[ks], kf, sf[st]);
            }
#pragma unroll
        for (int st = 0; st < 4; ++st)
#pragma unroll
            for (int r = 0; r < 4; ++r) {
                float pv = EXP2F(sf[st][r] * SCL);
                if (st * 16 + l16 > t0 + w * 16 + q * 4 + r) pv = 0.f;
                l_r[r] += pv;
                Pb[0][w * 16 + q * 4 + r][st * 16 + l16] = f2bf(pv);
            }
    }

    for (int ci = 0; ci < nch; ++ci) {
        __syncthreads();
        // ---- PV(ci) from Pb[ci&1] ----
        bf16x8 pf[4][2];
#pragma unroll
        for (int mt = 0; mt < 4; ++mt)
#pragma unroll
            for (int ks = 0; ks < 2; ++ks)
                pf[mt][ks] = *(bf16x8*)&Pb[ci & 1][mt * 16 + l16][ks * 32 + q * 8];
        const int s0 = ci * 64;
#pragma unroll
        for (int nt = 0; nt < 8; ++nt)
#pragma unroll
            for (int ks = 0; ks < 2; ++ks) {
                bf16x8 vf = *(const bf16x8*)(ztb +
                    (size_t)(nw + nt * 16 + l16) * 1024 + s0 + ks * 32 + q * 8);
#pragma unroll
                for (int mt = 0; mt < 4; ++mt)
                    acc[mt][nt] = MFMA16(pf[mt][ks], vf, acc[mt][nt]);
            }
        // ---- QK(ci+1) into Pb[(ci+1)&1] ----
        if (w < 4 && ci + 1 < nch) {
            const int s0c = (ci + 1) * 64, par = (ci + 1) & 1;
            f32x4 sf[4];
#pragma unroll
            for (int st = 0; st < 4; ++st) sf[st] = (f32x4){0.f, 0.f, 0.f, 0.f};
#pragma unroll
            for (int st = 0; st < 4; ++st)
#pragma unroll
                for (int ks = 0; ks < 2; ++ks) {
                    bf16x8 kf = *(const bf16x8*)(xbb +
                        (size_t)(s0c + st * 16 + l16) * 1024 + h * 64 + ks * 32 + q * 8);
                    sf[st] = MFMA16(qf[ks], kf, sf[st]);
                }
#pragma unroll
            for (int st = 0; st < 4; ++st)
#pragma unroll
                for (int r = 0; r < 4; ++r) {
                    float pv = EXP2F(sf[st][r] * SCL);
                    if (s0c + st * 16 + l16 > t0 + w * 16 + q * 4 + r) pv = 0.f;
                    l_r[r] += pv;
                    Pb[par][w * 16 + q * 4 + r][st * 16 + l16] = f2bf(pv);
                }
        }
    }

    // Reduce per-lane partial row sums, publish.
    if (w < 4) {
#pragma unroll
        for (int r = 0; r < 4; ++r) {
            l_r[r] += __shfl_xor(l_r[r], 1);
            l_r[r] += __shfl_xor(l_r[r], 2);
            l_r[r] += __shfl_xor(l_r[r], 4);
            l_r[r] += __shfl_xor(l_r[r], 8);
        }
        if (l16 == 0) {
#pragma unroll
            for (int r = 0; r < 4; ++r) row_l[w * 16 + q * 4 + r] = l_r[r];
        }
    }
    __syncthreads();

    // Epilogue: normalize + head-sum into out (pre-zeroed) via fp32 atomics.
#pragma unroll
    for (int mt = 0; mt < 4; ++mt) {
        float i0 = 1.f / row_l[mt * 16 + q * 4 + 0];
        float i1 = 1.f / row_l[mt * 16 + q * 4 + 1];
        float i2 = 1.f / row_l[mt * 16 + q * 4 + 2];
        float i3 = 1.f / row_l[mt * 16 + q * 4 + 3];
#pragma unroll
        for (int nt = 0; nt < 8; ++nt) {
            size_t base = (size_t)(b * 1024 + t0 + mt * 16 + q * 4) * 1024 +
                          nw + nt * 16 + l16;
            atomicAdd(out + base,        acc[mt][nt][0] * i0);
            atomicAdd(out + base + 1024, acc[mt][nt][1] * i1);
            atomicAdd(out + base + 2048, acc[mt][nt][2] * i2);
            atomicAdd(out + base + 3072, acc[mt][nt][3] * i3);
        }
    }
}

// ---------------------------------------------------------------------------
// Fallback Z-GEMM for small workspace (no Wt buffer): fp32 W staged in-kernel.
// Writes the same ZT[b][h][n][s] layout.
// ---------------------------------------------------------------------------
#define ZPAD 40

__global__ __launch_bounds__(256, 2) void zgemm_sm(const short* __restrict__ xb,
                                                   const float* __restrict__ W,
                                                   short* __restrict__ ZT) {
    __shared__ short Wts[128 * ZPAD];
    __shared__ short Xs[2][128 * ZPAD];

    const int tid = threadIdx.x;
    const int bs = blockIdx.x & 7;
    const int bn = (blockIdx.x >> 3) & 7;
    const int h  = blockIdx.x >> 6;
    const int s0 = bs * 128, n0 = bn * 128;
    const int lane = tid & 63, q = lane >> 4, l16 = lane & 15;
    const int w = tid >> 6, bw = w >> 1, sh = w & 1;

    f32x4 acc[8][4];
#pragma unroll
    for (int i = 0; i < 8; ++i)
#pragma unroll
        for (int j = 0; j < 4; ++j) acc[i][j] = (f32x4){0.f, 0.f, 0.f, 0.f};

    for (int k0 = 0; k0 < 1024; k0 += 32) {
        __syncthreads();
#pragma unroll
        for (int r = 0; r < 2; ++r) {
            const int c2 = ((tid >> 5) << 1) + (r << 4);
            const float* w0p = W + (size_t)(h * 1024 + k0 + c2) * 1024 + n0;
            const float* w1p = w0p + 1024;
#pragma unroll
            for (int i = 0; i < 4; ++i) {
                const int n = (tid & 31) + (i << 5);
                float wa = w0p[n], wb = w1p[n];
                unsigned u = (unsigned)(unsigned short)f2bf(wa) |
                             ((unsigned)(unsigned short)f2bf(wb) << 16);
                *(unsigned*)&Wts[n * ZPAD + c2] = u;
            }
        }
#pragma unroll
        for (int i = 0; i < 4; ++i) {
            const int id = tid + (i << 8);
            const int b2 = id >> 9, s = (id >> 2) & 127, cg = id & 3;
            bf16x8 v = *(const bf16x8*)(xb + (size_t)b2 * (T_ * C_) +
                                        (size_t)(s0 + s) * 1024 + k0 + cg * 8);
            *(bf16x8*)&Xs[b2][s * ZPAD + cg * 8] = v;
        }
        __syncthreads();

        bf16x8 af[8], bfr[4];
#pragma unroll
        for (int ntv = 0; ntv < 8; ++ntv)
            af[ntv] = *(bf16x8*)&Wts[(ntv * 16 + l16) * ZPAD + q * 8];
#pragma unroll
        for (int st = 0; st < 4; ++st)
            bfr[st] = *(bf16x8*)&Xs[bw][(sh * 64 + st * 16 + l16) * ZPAD + q * 8];
#pragma unroll
        for (int ntv = 0; ntv < 8; ++ntv)
#pragma unroll
            for (int st = 0; st < 4; ++st)
                acc[ntv][st] = MFMA16(af[ntv], bfr[st], acc[ntv][st]);
    }

    short* zb = ZT + (size_t)(bw * 16 + h) * (1024 * 1024);
#pragma unroll
    for (int ntv = 0; ntv < 8; ++ntv)
#pragma unroll
        for (int st = 0; st < 4; ++st)
#pragma unroll
            for (int r = 0; r < 4; ++r) {
                int n_abs = n0 + ntv * 16 + q * 4 + r;
                int s_abs = s0 + sh * 64 + st * 16 + l16;
                zb[(size_t)n_abs * 1024 + s_abs] = f2bf(acc[ntv][st][r]);
            }
}

// ---------------------------------------------------------------------------
extern "C" void kernel_launch(void* const* d_in, const int* in_sizes, int n_in,
                              void* d_out, int out_size, void* d_ws, size_t ws_size,
                              hipStream_t stream) {
    const float* x = (const float*)d_in[0];
    // d_in[1] (mask) recomputed analytically.
    const float* W = (const float*)d_in[2];
    float* out = (float*)d_out;

    const size_t MB = 1024 * 1024;
    short* xb = (short*)d_ws;                          // [0,   4 MiB)
    short* ZT = (short*)d_ws + 2 * MB;                 // [4,  68 MiB)  [b][h][n][s]
    short* Wt = (short*)d_ws + 34 * MB;                // [68, 100 MiB)

    (void)hipMemsetAsync(d_out, 0, (size_t)B_ * T_ * C_ * sizeof(float), stream);
    cvt_x<<<(B_ * T_ * C_) / (256 * 8), 256, 0, stream>>>(x, xb);

    if (ws_size >= 100 * MB) {
        cvt_w<<<16 * 16 * 16, 256, 0, stream>>>(W, Wt);
        zgemm4<<<128 * 16, 256, 0, stream>>>(xb, Wt, ZT);
    } else {
        zgemm_sm<<<H_ * 8 * 8, 256, 0, stream>>>(xb, W, ZT);
    }
    attn<<<512, 512, 0, stream>>>(xb, ZT, out);
}